// Round 13
// baseline (593.093 us; speedup 1.0000x reference)
//
#include <hip/hip_runtime.h>

// MSDNet on gfx950 — round 13: R12 (paired-channel fdot2 + bpermute windows)
// + channel-SPLIT across 2 waves per row. R12 budget: busy-pipe sum ~210us
// vs measured ~380us -> latency exposure at 8 waves/CU + per-wave serial
// chain. This round: block = 128 thr = 2 waves = ONE row; wave 0 computes
// channel pairs [0,NPh), wave 1 [NPh,NP); partial accs merged via a 2KB
// lane-major LDS exchange (+syncthreads), wave 0 finalizes/writes. Same
// total VMEM/fdot2; 2x waves/CU (16), half the per-wave critical path.
// __launch_bounds__(128,4) caps VGPR at 128 for 4 waves/SIMD residency.

#define MSD_DEPTH 30
#define NB 4
#define IH 512
#define IW 512
#define HALO 16
#define WPp (IW + 2 * HALO)               /* 544 u32 per row */
#define HPp (IH + 2 * HALO)               /* 544 rows */
#define PLANE_U ((size_t)WPp * HPp)       /* u32 per subplane */
#define PSTR ((size_t)NB * PLANE_U)       /* pair stride (u32) */
#define NPAIR 15
#define NPIX (NB * IH * IW)
#define WPK_OFF ((size_t)20 << 20)        /* u32 offset: 80 MB into ws */

typedef _Float16 h2v __attribute__((ext_vector_type(2)));
typedef unsigned int u32;

__device__ __forceinline__ float fdot2u(u32 a, u32 b, float c) {
#if __has_builtin(__builtin_amdgcn_fdot2)
    return __builtin_amdgcn_fdot2(__builtin_bit_cast(h2v, a),
                                  __builtin_bit_cast(h2v, b), c, false);
#else
    h2v x = __builtin_bit_cast(h2v, a), y = __builtin_bit_cast(h2v, b);
    return c + (float)x[0] * (float)y[0] + (float)x[1] * (float)y[1];
#endif
}

// ---------------------------------------------------------------------------
__global__ __launch_bounds__(256) void pack_weights(const float* __restrict__ Wmsd,
                                                    const float* __restrict__ convW,
                                                    u32* __restrict__ wpk,
                                                    u32* __restrict__ cpk) {
    int idx = blockIdx.x * 256 + threadIdx.x;
    if (idx < MSD_DEPTH * NPAIR * 9) {
        int I = idx / (NPAIR * 9);
        int rem = idx - I * (NPAIR * 9);
        int p = rem / 9, t = rem - p * 9;
        int NC = I + 1, c0 = 2 * p, c1 = 2 * p + 1;
        h2v pk;
        pk[0] = (_Float16)((c0 < NC) ? Wmsd[((size_t)I * MSD_DEPTH + c0) * 9 + t] : 0.f);
        pk[1] = (_Float16)((c1 < NC) ? Wmsd[((size_t)I * MSD_DEPTH + c1) * 9 + t] : 0.f);
        wpk[idx] = __builtin_bit_cast(u32, pk);
    }
    if (idx < NPAIR) {
        h2v pk;
        pk[0] = (_Float16)convW[2 * idx];
        pk[1] = (_Float16)convW[2 * idx + 1];
        cpk[idx] = __builtin_bit_cast(u32, pk);
    }
}

// ---------------------------------------------------------------------------
// Zero top/bottom 16 full rows of all 60 subplanes (side halos never read:
// horizontal zero-pad is synthesized by the bpermute validity masks).
__global__ __launch_bounds__(256) void zero_halo_kernel(u32* __restrict__ feats) {
    const int per = 32 * (WPp / 4); // 32 rows x 136 uint4 strips = 4352
    int idx = blockIdx.x * 256 + threadIdx.x;
    if (idx >= per * NPAIR * NB) return;
    int sub = idx / per;
    int s = idx - sub * per;
    int rr = s / 136;
    int c4 = (s - rr * 136) * 4;
    int r = (rr < 16) ? rr : (IH + HALO) + (rr - 16);
    uint4 z = {0, 0, 0, 0};
    *(uint4*)(feats + (size_t)sub * PLANE_U + (size_t)r * WPp + c4) = z;
}

// ---------------------------------------------------------------------------
// Pair 0 lo16 = f16(x*sin_w+sin_b), hi16 = 0 (h0 merged in by depth 0).
__global__ __launch_bounds__(256) void scale_in_kernel(const float* __restrict__ x,
                                                       u32* __restrict__ feats,
                                                       const float* __restrict__ sw,
                                                       const float* __restrict__ sb) {
    int s = blockIdx.x * 256 + threadIdx.x;
    int idx = s * 8;
    int b = idx >> 18;
    int y = (idx >> 9) & 511;
    int xx = idx & 511;
    const float sws = sw[0], sbs = sb[0];
    u32 v[8];
#pragma unroll
    for (int j = 0; j < 8; ++j) {
        _Float16 h = (_Float16)(x[idx + j] * sws + sbs);
        v[j] = (u32)__builtin_bit_cast(unsigned short, h);
    }
    u32* q = feats + (size_t)b * PLANE_U + (size_t)(y + HALO) * WPp + HALO + xx;
    *(uint4*)q = *(uint4*)&v[0];
    *(uint4*)(q + 4) = *(uint4*)&v[4];
}

// ---------------------------------------------------------------------------
template <int I>
__global__ __launch_bounds__(128, 4) void depth_kernel(u32* __restrict__ feats,
                                                       const u32* __restrict__ wpk,
                                                       const u32* __restrict__ cpk,
                                                       const float* __restrict__ bias,
                                                       const float* __restrict__ convW,
                                                       const float* __restrict__ convB,
                                                       const float* __restrict__ soutw,
                                                       const float* __restrict__ soutb,
                                                       float* __restrict__ out) {
    constexpr int D = (I % 10) + 1;
    constexpr int NC = I + 1;
    constexpr int NP = (NC + 1) / 2;
    constexpr int NPh = (NP + 1) / 2; // wave0: [0,NPh) wave1: [NPh,NP)
    constexpr bool LAST = (I == MSD_DEPTH - 1);

    __shared__ float redacc[8][64];
    __shared__ float redyd[LAST ? 8 : 1][64];

    const int tid = threadIdx.x;
    const int w = tid >> 6, lane = tid & 63;
    const int bid = blockIdx.x; // 2048 blocks = rows; 2 waves per row
    // XCD band swizzle (validated R4-R12): 2 XCDs per image, contiguous bands.
    const int xcd = bid & 7;
    const int kk = bid >> 3; // 0..255
    const int b = xcd >> 1;
    const int y = (xcd & 1) * 256 + kk;

    // bpermute byte addresses for lane offsets -2,-1,+1,+2 (wrap is masked).
    const int bp_m2 = ((lane - 2) & 63) << 2;
    const int bp_m1 = ((lane - 1) & 63) << 2;
    const int bp_p1 = ((lane + 1) & 63) << 2;
    const int bp_p2 = ((lane + 2) & 63) << 2;

    u32* const pb = feats + (size_t)b * PLANE_U + (size_t)(y + HALO) * WPp + HALO + lane * 8;

    float acc[8], ydot[8];
#pragma unroll
    for (int j = 0; j < 8; ++j) { acc[j] = 0.f; ydot[j] = 0.f; }

    const u32* const wrb = wpk + (size_t)I * (NPAIR * 9);

    u32 A[3][8], B[3][8];

    auto load_pair = [&](u32 (*buf)[8], int p) {
        const u32* pp = pb + (size_t)p * PSTR;
#pragma unroll
        for (int r = 0; r < 3; ++r) {
            const u32* rp = pp + (ptrdiff_t)(r - 1) * (D * WPp);
            *(uint4*)&buf[r][0] = *(const uint4*)rp;
            *(uint4*)&buf[r][4] = *(const uint4*)(rp + 4);
        }
    };

    // w[k] = dword at row-pixel (lane*8 + k + shift), 0 outside [0,512).
    auto window = [&](const u32* d, int shift, u32* wd) {
#pragma unroll
        for (int k = 0; k < 8; ++k) {
            int off = k + shift; // constant-folded (shift = +-D, k unrolled)
            if (off >= 0 && off < 8) {
                wd[k] = d[off];
            } else {
                int q = off >> 3;            // floor div 8: -2,-1,1,2
                int idx = off - q * 8;       // 0..7
                int addr = (q == -2) ? bp_m2
                         : (q == -1) ? bp_m1
                         : (q == 1)  ? bp_p1 : bp_p2;
                u32 t = (u32)__builtin_amdgcn_ds_bpermute(addr, (int)d[idx]);
                bool valid = (q < 0) ? (lane >= -q) : (lane <= 63 - q);
                wd[k] = valid ? t : 0u;
            }
        }
    };

    auto compute = [&](u32 (*buf)[8], int p) {
        const u32* wq = wrb + p * 9; // wave-uniform -> s_load
        const u32 cw = LAST ? cpk[p] : 0u;
#pragma unroll
        for (int r = 0; r < 3; ++r) {
            u32* d = buf[r];
            u32 wl[8], wrr[8];
            window(d, -D, wl);
            window(d, D, wrr);
            const u32 w0 = wq[r * 3 + 0], w1 = wq[r * 3 + 1], w2 = wq[r * 3 + 2];
#pragma unroll
            for (int k = 0; k < 8; ++k) {
                float a = acc[k];
                a = fdot2u(wl[k], w0, a);
                a = fdot2u(d[k], w1, a);
                a = fdot2u(wrr[k], w2, a);
                acc[k] = a;
            }
            if (LAST && r == 1) {
#pragma unroll
                for (int k = 0; k < 8; ++k) ydot[k] = fdot2u(d[k], cw, ydot[k]);
            }
        }
    };

    // This wave's pair range; 2-deep software pipeline (validated R8/R12).
    const int p0 = w ? NPh : 0;
    const int p1 = w ? NP : NPh;
    if (p1 > p0) {
        load_pair(A, p0);
        int p = p0;
        for (; p + 2 <= p1; p += 2) {
            load_pair(B, p + 1);
            compute(A, p);
            if (p + 2 < p1) load_pair(A, p + 2);
            compute(B, p + 1);
        }
        if (p < p1) compute(A, p);
    }

    // Cross-wave reduction: wave 1 -> LDS, wave 0 merges and finalizes.
    if (w == 1) {
#pragma unroll
        for (int j = 0; j < 8; ++j) redacc[j][lane] = acc[j];
        if constexpr (LAST) {
#pragma unroll
            for (int j = 0; j < 8; ++j) redyd[j][lane] = ydot[j];
        }
    }
    __syncthreads();
    if (w != 0) return;
#pragma unroll
    for (int j = 0; j < 8; ++j) acc[j] += redacc[j][lane];
    if constexpr (LAST) {
#pragma unroll
        for (int j = 0; j < 8; ++j) ydot[j] += redyd[j][lane];
    }

    const float b0 = bias[I];
    if (!LAST) {
        // Merge h (channel NC) into pair NC>>1. NC odd: hi16 (partner lo16 =
        // channel NC-1, reloaded L2-hot). NC even: lo16, hi16 = 0.
        u32 part[8];
        if constexpr ((NC & 1) != 0) {
            const u32* rp = pb + (size_t)(NP - 1) * PSTR;
            *(uint4*)&part[0] = *(const uint4*)rp;
            *(uint4*)&part[4] = *(const uint4*)(rp + 4);
        }
        u32 mg[8];
#pragma unroll
        for (int j = 0; j < 8; ++j) {
            float h = acc[j] + b0;
            h = h > 0.f ? h : 0.f;
            u32 h16 = (u32)__builtin_bit_cast(unsigned short, (_Float16)h);
            if constexpr ((NC & 1) != 0)
                mg[j] = (part[j] & 0xFFFFu) | (h16 << 16);
            else
                mg[j] = h16;
        }
        u32* q = feats + (size_t)(NC >> 1) * PSTR + (size_t)b * PLANE_U +
                 (size_t)(y + HALO) * WPp + HALO + lane * 8;
        *(uint4*)q = *(uint4*)&mg[0];
        *(uint4*)(q + 4) = *(uint4*)&mg[4];
    } else {
        const float cw30 = convW[MSD_DEPTH];
        const float cb = convB[0], ow = soutw[0], ob = soutb[0];
        float* q = out + ((size_t)b * IH + y) * IW + lane * 8;
        float o[8];
#pragma unroll
        for (int j = 0; j < 8; ++j) {
            float h = acc[j] + b0;
            h = h > 0.f ? h : 0.f;
            float yv = ydot[j] + cw30 * h + cb;
            o[j] = yv * ow + ob;
        }
        *(uint4*)q = *(uint4*)&o[0];
        *(uint4*)(q + 4) = *(uint4*)&o[4];
    }
}

// ---------------------------------------------------------------------------
extern "C" void kernel_launch(void* const* d_in, const int* in_sizes, int n_in,
                              void* d_out, int out_size, void* d_ws, size_t ws_size,
                              hipStream_t stream) {
    const float* x     = (const float*)d_in[0];
    const float* Wmsd  = (const float*)d_in[1];
    const float* bias  = (const float*)d_in[2];
    const float* convW = (const float*)d_in[3];
    const float* convB = (const float*)d_in[4];
    const float* sinw  = (const float*)d_in[5];
    const float* sinb  = (const float*)d_in[6];
    const float* soutw = (const float*)d_in[7];
    const float* soutb = (const float*)d_in[8];
    float* out = (float*)d_out;

    u32* feats = (u32*)d_ws;                 // 15 pairs x 4 b x 544x544 u32 = 71 MB
    u32* wpk = feats + WPK_OFF;              // 80 MB offset
    u32* cpk = wpk + MSD_DEPTH * NPAIR * 9;

    pack_weights<<<16, 256, 0, stream>>>(Wmsd, convW, wpk, cpk);

    const int zstrips = 32 * (WPp / 4) * NPAIR * NB; // 261120
    zero_halo_kernel<<<(zstrips + 255) / 256, 256, 0, stream>>>(feats);

    scale_in_kernel<<<NPIX / 8 / 256, 256, 0, stream>>>(x, feats, sinw, sinb);

#define LNCH(I) depth_kernel<I><<<2048, 128, 0, stream>>>(feats, wpk, cpk, bias, convW, convB, soutw, soutb, out);
    LNCH(0)  LNCH(1)  LNCH(2)  LNCH(3)  LNCH(4)
    LNCH(5)  LNCH(6)  LNCH(7)  LNCH(8)  LNCH(9)
    LNCH(10) LNCH(11) LNCH(12) LNCH(13) LNCH(14)
    LNCH(15) LNCH(16) LNCH(17) LNCH(18) LNCH(19)
    LNCH(20) LNCH(21) LNCH(22) LNCH(23) LNCH(24)
    LNCH(25) LNCH(26) LNCH(27) LNCH(28) LNCH(29)
#undef LNCH
}

// Round 14
// 446.847 us; speedup vs baseline: 1.3273x; 1.3273x over previous
//
#include <hip/hip_runtime.h>

// MSDNet on gfx950 — round 14: R13 channel-split retried WITHOUT the VGPR cap.
// R13 regressed purely from __launch_bounds__(128,4): VGPR forced to 64 ->
// scratch spills (WRITE_SIZE 162MB/dispatch vs ~4MB real output). This round
// is R13 verbatim with __launch_bounds__(128,2) (cap 256): expected VGPR
// ~110-130, no spill, HW residency 4 waves/SIMD = 16 waves/CU — the
// occupancy the split was designed to buy.
// Structure: feats = 15 channel-pairs (u32 = 2xf16) x 4 batches x 544x544;
// block = 128 thr = 2 waves = ONE row; wave 0 computes pairs [0,NPh),
// wave 1 [NPh,NP); partials merged via LDS; wave 0 finalizes/writes.
// fdot2 contracts 2 ch/px/tap; bpermute windows synthesize +-D with
// zero-pad masks; 2-deep pair pipeline; weights pre-packed f16 pairs.

#define MSD_DEPTH 30
#define NB 4
#define IH 512
#define IW 512
#define HALO 16
#define WPp (IW + 2 * HALO)               /* 544 u32 per row */
#define HPp (IH + 2 * HALO)               /* 544 rows */
#define PLANE_U ((size_t)WPp * HPp)       /* u32 per subplane */
#define PSTR ((size_t)NB * PLANE_U)       /* pair stride (u32) */
#define NPAIR 15
#define NPIX (NB * IH * IW)
#define WPK_OFF ((size_t)20 << 20)        /* u32 offset: 80 MB into ws */

typedef _Float16 h2v __attribute__((ext_vector_type(2)));
typedef unsigned int u32;

__device__ __forceinline__ float fdot2u(u32 a, u32 b, float c) {
#if __has_builtin(__builtin_amdgcn_fdot2)
    return __builtin_amdgcn_fdot2(__builtin_bit_cast(h2v, a),
                                  __builtin_bit_cast(h2v, b), c, false);
#else
    h2v x = __builtin_bit_cast(h2v, a), y = __builtin_bit_cast(h2v, b);
    return c + (float)x[0] * (float)y[0] + (float)x[1] * (float)y[1];
#endif
}

// ---------------------------------------------------------------------------
__global__ __launch_bounds__(256) void pack_weights(const float* __restrict__ Wmsd,
                                                    const float* __restrict__ convW,
                                                    u32* __restrict__ wpk,
                                                    u32* __restrict__ cpk) {
    int idx = blockIdx.x * 256 + threadIdx.x;
    if (idx < MSD_DEPTH * NPAIR * 9) {
        int I = idx / (NPAIR * 9);
        int rem = idx - I * (NPAIR * 9);
        int p = rem / 9, t = rem - p * 9;
        int NC = I + 1, c0 = 2 * p, c1 = 2 * p + 1;
        h2v pk;
        pk[0] = (_Float16)((c0 < NC) ? Wmsd[((size_t)I * MSD_DEPTH + c0) * 9 + t] : 0.f);
        pk[1] = (_Float16)((c1 < NC) ? Wmsd[((size_t)I * MSD_DEPTH + c1) * 9 + t] : 0.f);
        wpk[idx] = __builtin_bit_cast(u32, pk);
    }
    if (idx < NPAIR) {
        h2v pk;
        pk[0] = (_Float16)convW[2 * idx];
        pk[1] = (_Float16)convW[2 * idx + 1];
        cpk[idx] = __builtin_bit_cast(u32, pk);
    }
}

// ---------------------------------------------------------------------------
// Zero top/bottom 16 full rows of all 60 subplanes (side halos never read:
// horizontal zero-pad is synthesized by the bpermute validity masks).
__global__ __launch_bounds__(256) void zero_halo_kernel(u32* __restrict__ feats) {
    const int per = 32 * (WPp / 4); // 32 rows x 136 uint4 strips = 4352
    int idx = blockIdx.x * 256 + threadIdx.x;
    if (idx >= per * NPAIR * NB) return;
    int sub = idx / per;
    int s = idx - sub * per;
    int rr = s / 136;
    int c4 = (s - rr * 136) * 4;
    int r = (rr < 16) ? rr : (IH + HALO) + (rr - 16);
    uint4 z = {0, 0, 0, 0};
    *(uint4*)(feats + (size_t)sub * PLANE_U + (size_t)r * WPp + c4) = z;
}

// ---------------------------------------------------------------------------
// Pair 0 lo16 = f16(x*sin_w+sin_b), hi16 = 0 (h0 merged in by depth 0).
__global__ __launch_bounds__(256) void scale_in_kernel(const float* __restrict__ x,
                                                       u32* __restrict__ feats,
                                                       const float* __restrict__ sw,
                                                       const float* __restrict__ sb) {
    int s = blockIdx.x * 256 + threadIdx.x;
    int idx = s * 8;
    int b = idx >> 18;
    int y = (idx >> 9) & 511;
    int xx = idx & 511;
    const float sws = sw[0], sbs = sb[0];
    u32 v[8];
#pragma unroll
    for (int j = 0; j < 8; ++j) {
        _Float16 h = (_Float16)(x[idx + j] * sws + sbs);
        v[j] = (u32)__builtin_bit_cast(unsigned short, h);
    }
    u32* q = feats + (size_t)b * PLANE_U + (size_t)(y + HALO) * WPp + HALO + xx;
    *(uint4*)q = *(uint4*)&v[0];
    *(uint4*)(q + 4) = *(uint4*)&v[4];
}

// ---------------------------------------------------------------------------
template <int I>
__global__ __launch_bounds__(128, 2) void depth_kernel(u32* __restrict__ feats,
                                                       const u32* __restrict__ wpk,
                                                       const u32* __restrict__ cpk,
                                                       const float* __restrict__ bias,
                                                       const float* __restrict__ convW,
                                                       const float* __restrict__ convB,
                                                       const float* __restrict__ soutw,
                                                       const float* __restrict__ soutb,
                                                       float* __restrict__ out) {
    constexpr int D = (I % 10) + 1;
    constexpr int NC = I + 1;
    constexpr int NP = (NC + 1) / 2;
    constexpr int NPh = (NP + 1) / 2; // wave0: [0,NPh) wave1: [NPh,NP)
    constexpr bool LAST = (I == MSD_DEPTH - 1);

    __shared__ float redacc[8][64];
    __shared__ float redyd[LAST ? 8 : 1][64];

    const int tid = threadIdx.x;
    const int w = tid >> 6, lane = tid & 63;
    const int bid = blockIdx.x; // 2048 blocks = rows; 2 waves per row
    // XCD band swizzle (validated R4-R12): 2 XCDs per image, contiguous bands.
    const int xcd = bid & 7;
    const int kk = bid >> 3; // 0..255
    const int b = xcd >> 1;
    const int y = (xcd & 1) * 256 + kk;

    // bpermute byte addresses for lane offsets -2,-1,+1,+2 (wrap is masked).
    const int bp_m2 = ((lane - 2) & 63) << 2;
    const int bp_m1 = ((lane - 1) & 63) << 2;
    const int bp_p1 = ((lane + 1) & 63) << 2;
    const int bp_p2 = ((lane + 2) & 63) << 2;

    u32* const pb = feats + (size_t)b * PLANE_U + (size_t)(y + HALO) * WPp + HALO + lane * 8;

    float acc[8], ydot[8];
#pragma unroll
    for (int j = 0; j < 8; ++j) { acc[j] = 0.f; ydot[j] = 0.f; }

    const u32* const wrb = wpk + (size_t)I * (NPAIR * 9);

    u32 A[3][8], B[3][8];

    auto load_pair = [&](u32 (*buf)[8], int p) {
        const u32* pp = pb + (size_t)p * PSTR;
#pragma unroll
        for (int r = 0; r < 3; ++r) {
            const u32* rp = pp + (ptrdiff_t)(r - 1) * (D * WPp);
            *(uint4*)&buf[r][0] = *(const uint4*)rp;
            *(uint4*)&buf[r][4] = *(const uint4*)(rp + 4);
        }
    };

    // w[k] = dword at row-pixel (lane*8 + k + shift), 0 outside [0,512).
    auto window = [&](const u32* d, int shift, u32* wd) {
#pragma unroll
        for (int k = 0; k < 8; ++k) {
            int off = k + shift; // constant-folded (shift = +-D, k unrolled)
            if (off >= 0 && off < 8) {
                wd[k] = d[off];
            } else {
                int q = off >> 3;            // floor div 8: -2,-1,1,2
                int idx = off - q * 8;       // 0..7
                int addr = (q == -2) ? bp_m2
                         : (q == -1) ? bp_m1
                         : (q == 1)  ? bp_p1 : bp_p2;
                u32 t = (u32)__builtin_amdgcn_ds_bpermute(addr, (int)d[idx]);
                bool valid = (q < 0) ? (lane >= -q) : (lane <= 63 - q);
                wd[k] = valid ? t : 0u;
            }
        }
    };

    auto compute = [&](u32 (*buf)[8], int p) {
        const u32* wq = wrb + p * 9; // wave-uniform -> s_load
        const u32 cw = LAST ? cpk[p] : 0u;
#pragma unroll
        for (int r = 0; r < 3; ++r) {
            u32* d = buf[r];
            u32 wl[8], wrr[8];
            window(d, -D, wl);
            window(d, D, wrr);
            const u32 w0 = wq[r * 3 + 0], w1 = wq[r * 3 + 1], w2 = wq[r * 3 + 2];
#pragma unroll
            for (int k = 0; k < 8; ++k) {
                float a = acc[k];
                a = fdot2u(wl[k], w0, a);
                a = fdot2u(d[k], w1, a);
                a = fdot2u(wrr[k], w2, a);
                acc[k] = a;
            }
            if (LAST && r == 1) {
#pragma unroll
                for (int k = 0; k < 8; ++k) ydot[k] = fdot2u(d[k], cw, ydot[k]);
            }
        }
    };

    // This wave's pair range; 2-deep software pipeline (validated R8/R12).
    const int p0 = w ? NPh : 0;
    const int p1 = w ? NP : NPh;
    if (p1 > p0) {
        load_pair(A, p0);
        int p = p0;
        for (; p + 2 <= p1; p += 2) {
            load_pair(B, p + 1);
            compute(A, p);
            if (p + 2 < p1) load_pair(A, p + 2);
            compute(B, p + 1);
        }
        if (p < p1) compute(A, p);
    }

    // Cross-wave reduction: wave 1 -> LDS, wave 0 merges and finalizes.
    if (w == 1) {
#pragma unroll
        for (int j = 0; j < 8; ++j) redacc[j][lane] = acc[j];
        if constexpr (LAST) {
#pragma unroll
            for (int j = 0; j < 8; ++j) redyd[j][lane] = ydot[j];
        }
    }
    __syncthreads();
    if (w != 0) return;
#pragma unroll
    for (int j = 0; j < 8; ++j) acc[j] += redacc[j][lane];
    if constexpr (LAST) {
#pragma unroll
        for (int j = 0; j < 8; ++j) ydot[j] += redyd[j][lane];
    }

    const float b0 = bias[I];
    if (!LAST) {
        // Merge h (channel NC) into pair NC>>1. NC odd: hi16 (partner lo16 =
        // channel NC-1, reloaded L2-hot). NC even: lo16, hi16 = 0.
        u32 part[8];
        if constexpr ((NC & 1) != 0) {
            const u32* rp = pb + (size_t)(NP - 1) * PSTR;
            *(uint4*)&part[0] = *(const uint4*)rp;
            *(uint4*)&part[4] = *(const uint4*)(rp + 4);
        }
        u32 mg[8];
#pragma unroll
        for (int j = 0; j < 8; ++j) {
            float h = acc[j] + b0;
            h = h > 0.f ? h : 0.f;
            u32 h16 = (u32)__builtin_bit_cast(unsigned short, (_Float16)h);
            if constexpr ((NC & 1) != 0)
                mg[j] = (part[j] & 0xFFFFu) | (h16 << 16);
            else
                mg[j] = h16;
        }
        u32* q = feats + (size_t)(NC >> 1) * PSTR + (size_t)b * PLANE_U +
                 (size_t)(y + HALO) * WPp + HALO + lane * 8;
        *(uint4*)q = *(uint4*)&mg[0];
        *(uint4*)(q + 4) = *(uint4*)&mg[4];
    } else {
        const float cw30 = convW[MSD_DEPTH];
        const float cb = convB[0], ow = soutw[0], ob = soutb[0];
        float* q = out + ((size_t)b * IH + y) * IW + lane * 8;
        float o[8];
#pragma unroll
        for (int j = 0; j < 8; ++j) {
            float h = acc[j] + b0;
            h = h > 0.f ? h : 0.f;
            float yv = ydot[j] + cw30 * h + cb;
            o[j] = yv * ow + ob;
        }
        *(uint4*)q = *(uint4*)&o[0];
        *(uint4*)(q + 4) = *(uint4*)&o[4];
    }
}

// ---------------------------------------------------------------------------
extern "C" void kernel_launch(void* const* d_in, const int* in_sizes, int n_in,
                              void* d_out, int out_size, void* d_ws, size_t ws_size,
                              hipStream_t stream) {
    const float* x     = (const float*)d_in[0];
    const float* Wmsd  = (const float*)d_in[1];
    const float* bias  = (const float*)d_in[2];
    const float* convW = (const float*)d_in[3];
    const float* convB = (const float*)d_in[4];
    const float* sinw  = (const float*)d_in[5];
    const float* sinb  = (const float*)d_in[6];
    const float* soutw = (const float*)d_in[7];
    const float* soutb = (const float*)d_in[8];
    float* out = (float*)d_out;

    u32* feats = (u32*)d_ws;                 // 15 pairs x 4 b x 544x544 u32 = 71 MB
    u32* wpk = feats + WPK_OFF;              // 80 MB offset
    u32* cpk = wpk + MSD_DEPTH * NPAIR * 9;

    pack_weights<<<16, 256, 0, stream>>>(Wmsd, convW, wpk, cpk);

    const int zstrips = 32 * (WPp / 4) * NPAIR * NB; // 261120
    zero_halo_kernel<<<(zstrips + 255) / 256, 256, 0, stream>>>(feats);

    scale_in_kernel<<<NPIX / 8 / 256, 256, 0, stream>>>(x, feats, sinw, sinb);

#define LNCH(I) depth_kernel<I><<<2048, 128, 0, stream>>>(feats, wpk, cpk, bias, convW, convB, soutw, soutb, out);
    LNCH(0)  LNCH(1)  LNCH(2)  LNCH(3)  LNCH(4)
    LNCH(5)  LNCH(6)  LNCH(7)  LNCH(8)  LNCH(9)
    LNCH(10) LNCH(11) LNCH(12) LNCH(13) LNCH(14)
    LNCH(15) LNCH(16) LNCH(17) LNCH(18) LNCH(19)
    LNCH(20) LNCH(21) LNCH(22) LNCH(23) LNCH(24)
    LNCH(25) LNCH(26) LNCH(27) LNCH(28) LNCH(29)
#undef LNCH
}